// Round 5
// baseline (272.099 us; speedup 1.0000x reference)
//
#include <hip/hip_runtime.h>

// ---------------------------------------------------------------------------
// MHLP predictor — fused f16 MFMA, full-occupancy + sigmoid round.
// R21 post-mortem (91 us): VALUBusy 71% @ Occ 36%, conflicts down 3.5x ->
// latency component left; LDS still the occupancy cap (36.9 KB/block).
// This round:
//   * LDS overlay: h[2176], arch[1152], ctx[2304], pool[1152] are
//     temporally disjoint (each dies when its frags are read; same-wave DS
//     ops are in-order) -> ONE 2304-u16 region per wave. 18432 B/block ->
//     8 blk/CU = 32 waves/CU (100%). __launch_bounds__(256,8) pins VGPR<=64
//     (compiler already chose 64).
//   * softmax over 2 keys == sigmoid(score diff): ctx = v0 + sig(d)*(v1-v0).
//     1 exp + 1 rcp per (head,r,tok) instead of 2 exp + max + rcp + 2 mul.
//   * k-bias cancels in k1-k0: drop its adds and loads entirely.
// Timeline per wave region [0,2304): S1 writes h (stride 136) -> S2 reads
// a2-frags, writes arch @0 (stride 72) -> S3 reads at1-frags -> S4 writes
// ctx[32][72] -> S5 reads ca-frags, writes pool @0 -> S6 reads pa-frags.
// Predict: Occ 36->65-85%, VALU ~90%, dur 91 -> ~55-65 us; absmax ~1e-3.
// ---------------------------------------------------------------------------

using s8v = __attribute__((ext_vector_type(8))) short;
using h8  = __attribute__((ext_vector_type(8))) _Float16;
using f4  = __attribute__((ext_vector_type(4))) float;

// d_ws u16-unit layout (pre-swizzled f16 weight frags)
#define WF_W1   0        // 12288  (K=75(+bias row 75)->KS=3, NT=8)
#define WF_W2   12288    // 8192   (K=128->KS=4, NT=4)
#define WF_IP   20480    // 12288  (K=64->KS=2, NT=12)
#define WF_OP   32768    // 4096   (K=64->KS=2, NT=4)
#define WF_W3   36864    // 2048   (K=64->KS=2, NT=2)
#define WF_HWE  38912    // 256    (hw_embed f16 [4][64])

// per-wave LDS: single overlaid region
#define PWS     2304     // u16; 4608 B per wave

__device__ __forceinline__ unsigned short f2h(float f) {
  _Float16 h = (_Float16)f;
  return __builtin_bit_cast(unsigned short, h);
}

// swizzle W[N][Kreal] row-major f32 -> B-frag f16 layout; optional bias row
// at k == Kreal (folded-bias trick).
__device__ __forceinline__ void swz(const float* __restrict__ W,
                                    const float* __restrict__ bias,
                                    unsigned short* __restrict__ dst,
                                    int Kreal, int KS, int NT, int t, int stride) {
  const int total = KS * NT * 512;
  for (int i = t; i < total; i += stride) {
    const int j = i & 7, ln = (i >> 3) & 63, fr = i >> 9;
    const int nt = fr % NT, ks = fr / NT;
    const int n = nt * 16 + (ln & 15);
    const int k = ks * 32 + (ln >> 4) * 8 + j;
    float v = 0.f;
    if (k < Kreal) v = W[n * Kreal + k];
    else if (bias && k == Kreal) v = bias[n];
    dst[i] = f2h(v);
  }
}

__global__ void k_pre(const float* __restrict__ hwe,
                      const float* __restrict__ W1, const float* __restrict__ b1,
                      const float* __restrict__ W2,
                      const float* __restrict__ ipw, const float* __restrict__ opw,
                      const float* __restrict__ W3,
                      unsigned short* __restrict__ ws) {
  const int t = blockIdx.x * 256 + threadIdx.x;
  const int stride = gridDim.x * 256;
  swz(W1,  b1,      ws + WF_W1, 75, 3, 8, t, stride);
  swz(W2,  nullptr, ws + WF_W2, 128, 4, 4, t, stride);
  swz(ipw, nullptr, ws + WF_IP, 64, 2, 12, t, stride);
  swz(opw, nullptr, ws + WF_OP, 64, 2, 4, t, stride);
  swz(W3,  nullptr, ws + WF_W3, 64, 2, 2, t, stride);
  for (int i = t; i < 256; i += stride) ws[WF_HWE + i] = f2h(hwe[i]);
}

// ======================= fused: encoder + attention + head =================
__global__ __launch_bounds__(256, 8) void k_fused(
    const int* __restrict__ g_hw,
    const int* __restrict__ g_op, const int* __restrict__ g_wd,
    const float* __restrict__ g_hwe,
    const float* __restrict__ g_b2,
    const float* __restrict__ g_ln1g, const float* __restrict__ g_ln1b,
    const float* __restrict__ g_ipb, const float* __restrict__ g_opb,
    const float* __restrict__ g_ln2g, const float* __restrict__ g_ln2b,
    const float* __restrict__ g_b3,  const float* __restrict__ g_W4,
    const float* __restrict__ g_b4,
    const unsigned short* __restrict__ wsf,   // d_ws base (u16)
    float* __restrict__ g_out) {
  __shared__ __align__(16) unsigned short sm[4 * PWS];
  const int tid = threadIdx.x;
  const int wave = tid >> 6, lane = tid & 63;
  const int quad = lane >> 4, l15 = lane & 15;
  unsigned short* pw = sm + wave * PWS;
  const int m0 = (blockIdx.x * 4 + wave) * 16;   // 4096 blocks x 4 waves

  // ---- index loads (lanes 0..15) + in-wave broadcasts ----
  int hwv = 0, c0 = 0, c1 = 0, c2 = 0, c3 = 0, c4 = 0;
  if (lane < 16) {
    const int smp = m0 + lane;
    hwv = g_hw[smp];
    c0 =      g_op[smp * 5 + 0] * 3 + g_wd[smp * 5 + 0];
    c1 = 15 + g_op[smp * 5 + 1] * 3 + g_wd[smp * 5 + 1];
    c2 = 30 + g_op[smp * 5 + 2] * 3 + g_wd[smp * 5 + 2];
    c3 = 45 + g_op[smp * 5 + 3] * 3 + g_wd[smp * 5 + 3];
    c4 = 60 + g_op[smp * 5 + 4] * 3 + g_wd[smp * 5 + 4];
  }
  const int t0 = __shfl(c0, l15), t1 = __shfl(c1, l15), t2 = __shfl(c2, l15);
  const int t3 = __shfl(c3, l15), t4 = __shfl(c4, l15);
  const int hwrow = __shfl(hwv, l15);

  // ---- hoisted bias/param loads (one burst; L1-resident after 1st block) --
  float b2v[4], l1gv[4], l1bv[4], opbv[4], l2gv[4], l2bv[4];
#pragma unroll
  for (int nt = 0; nt < 4; ++nt) {
    const int col = nt * 16 + l15;
    b2v[nt] = g_b2[col];  l1gv[nt] = g_ln1g[col]; l1bv[nt] = g_ln1b[col];
    opbv[nt] = g_opb[col]; l2gv[nt] = g_ln2g[col]; l2bv[nt] = g_ln2b[col];
  }
  float ipbq[4], ipbvv[4];   // q-bias and v-bias; k-bias cancels in k1-k0
#pragma unroll
  for (int h = 0; h < 4; ++h) {
    ipbq[h]  = g_ipb[h * 16 + l15];
    ipbvv[h] = g_ipb[(h + 8) * 16 + l15];
  }
  float b3v[2], w4vv[2];
#pragma unroll
  for (int nt = 0; nt < 2; ++nt) {
    b3v[nt] = g_b3[nt * 16 + l15];
    w4vv[nt] = g_W4[nt * 16 + l15];
  }
  const float b4v = g_b4[0];

  // ---- one-hot A-frags (k==75 is the folded-bias row, always 1) ----
  h8 aoh[3];
#pragma unroll
  for (int ks = 0; ks < 3; ++ks) {
    s8v a;
#pragma unroll
    for (int j = 0; j < 8; ++j) {
      const int k = ks * 32 + quad * 8 + j;
      const bool hit = (k == 75) || (k == t0) || (k == t1) || (k == t2) ||
                       (k == t3) || (k == t4);
      a[j] = hit ? (short)0x3C00 : (short)0;   // f16 1.0
    }
    aoh[ks] = __builtin_bit_cast(h8, a);
  }

  // S1: h = relu(onehot @ [W1;b1]^T) -> pw[0..2176) stride 136 (f16)
#pragma unroll
  for (int nt = 0; nt < 8; ++nt) {
    f4 acc = {0.f, 0.f, 0.f, 0.f};
#pragma unroll
    for (int ks = 0; ks < 3; ++ks) {
      const h8 bf = *(const h8*)(wsf + WF_W1 + ((ks * 8 + nt) * 64 + lane) * 8);
      acc = __builtin_amdgcn_mfma_f32_16x16x32_f16(aoh[ks], bf, acc, 0, 0, 0);
    }
    const int col = nt * 16 + l15;
#pragma unroll
    for (int r = 0; r < 4; ++r) {
      float v = acc[r];
      v = v > 0.f ? v : 0.f;
      pw[(quad * 4 + r) * 136 + col] = f2h(v);
    }
  }

  // S2: arch = LN1(h @ W2^T + b2); arch f16 -> pw@0 stride 72 (h dead after
  // a2 reads; same-wave DS ops are in-order), residual f32 in regs.
  h8 a2[4];
#pragma unroll
  for (int ks = 0; ks < 4; ++ks)
    a2[ks] = *(const h8*)(pw + l15 * 136 + ks * 32 + quad * 8);
  float archres[4][4];   // LN1 out f32, layout (row=quad*4+r, col=nt*16+l15)
  {
    float val[4][4];
#pragma unroll
    for (int nt = 0; nt < 4; ++nt) {
      f4 acc = {0.f, 0.f, 0.f, 0.f};
#pragma unroll
      for (int ks = 0; ks < 4; ++ks) {
        const h8 bf = *(const h8*)(wsf + WF_W2 + ((ks * 4 + nt) * 64 + lane) * 8);
        acc = __builtin_amdgcn_mfma_f32_16x16x32_f16(a2[ks], bf, acc, 0, 0, 0);
      }
#pragma unroll
      for (int r = 0; r < 4; ++r) val[nt][r] = acc[r] + b2v[nt];
    }
#pragma unroll
    for (int r = 0; r < 4; ++r) {
      float s = val[0][r] + val[1][r] + val[2][r] + val[3][r];
      float q = val[0][r] * val[0][r] + val[1][r] * val[1][r] +
                val[2][r] * val[2][r] + val[3][r] * val[3][r];
#pragma unroll
      for (int off = 1; off <= 8; off <<= 1) {
        s += __shfl_xor(s, off);
        q += __shfl_xor(q, off);
      }
      const float mean = s * (1.f / 64.f);
      const float var  = q * (1.f / 64.f) - mean * mean;
      const float rstd = rsqrtf(var + 1e-5f);
#pragma unroll
      for (int nt = 0; nt < 4; ++nt) {
        const int col = nt * 16 + l15;
        const float xn = (val[nt][r] - mean) * rstd * l1gv[nt] + l1bv[nt];
        archres[nt][r] = xn;
        pw[(quad * 4 + r) * 72 + col] = f2h(xn);
      }
    }
  }

  // S3+S4 fused PER HEAD: qkv MFMAs -> in-register score-diff / sigmoid /
  // ctx. ctx[32][72] f16 -> pw@0 (arch dead after at1 reads).
  h8 at0[2], at1[2];
#pragma unroll
  for (int ks = 0; ks < 2; ++ks) {
    at0[ks] = *(const h8*)(wsf + WF_HWE + hwrow * 64 + ks * 32 + quad * 8);
    at1[ks] = *(const h8*)(pw + l15 * 72 + ks * 32 + quad * 8);
  }
#pragma unroll
  for (int h = 0; h < 4; ++h) {
    f4 aq0 = {0.f,0.f,0.f,0.f}, aq1 = {0.f,0.f,0.f,0.f};
    f4 ak0 = {0.f,0.f,0.f,0.f}, ak1 = {0.f,0.f,0.f,0.f};
    f4 av0 = {0.f,0.f,0.f,0.f}, av1 = {0.f,0.f,0.f,0.f};
#pragma unroll
    for (int ks = 0; ks < 2; ++ks) {
      const h8 bq = *(const h8*)(wsf + WF_IP + ((ks * 12 + h    ) * 64 + lane) * 8);
      const h8 bk = *(const h8*)(wsf + WF_IP + ((ks * 12 + h + 4) * 64 + lane) * 8);
      const h8 bv = *(const h8*)(wsf + WF_IP + ((ks * 12 + h + 8) * 64 + lane) * 8);
      aq0 = __builtin_amdgcn_mfma_f32_16x16x32_f16(at0[ks], bq, aq0, 0, 0, 0);
      aq1 = __builtin_amdgcn_mfma_f32_16x16x32_f16(at1[ks], bq, aq1, 0, 0, 0);
      ak0 = __builtin_amdgcn_mfma_f32_16x16x32_f16(at0[ks], bk, ak0, 0, 0, 0);
      ak1 = __builtin_amdgcn_mfma_f32_16x16x32_f16(at1[ks], bk, ak1, 0, 0, 0);
      av0 = __builtin_amdgcn_mfma_f32_16x16x32_f16(at0[ks], bv, av0, 0, 0, 0);
      av1 = __builtin_amdgcn_mfma_f32_16x16x32_f16(at1[ks], bv, av1, 0, 0, 0);
    }
    // score diffs d[qt] = q[qt]·(k1-k0) (k-bias cancels), reduce over l15
    float d0[4], d1[4], v0[4], v1[4];
#pragma unroll
    for (int r = 0; r < 4; ++r) {
      const float dk = ak1[r] - ak0[r];
      d0[r] = (aq0[r] + ipbq[h]) * dk;
      d1[r] = (aq1[r] + ipbq[h]) * dk;
      v0[r] = av0[r] + ipbvv[h];
      v1[r] = av1[r] + ipbvv[h];
    }
#pragma unroll
    for (int off = 1; off <= 8; off <<= 1)
#pragma unroll
      for (int r = 0; r < 4; ++r) {
        d0[r] += __shfl_xor(d0[r], off);
        d1[r] += __shfl_xor(d1[r], off);
      }
    // softmax over 2 keys == sigmoid(score diff); ctx lane-local
#pragma unroll
    for (int r = 0; r < 4; ++r) {
      const float a01 = 1.f / (1.f + __expf(-d0[r] * 0.25f));
      const float a11 = 1.f / (1.f + __expf(-d1[r] * 0.25f));
      const float dv = v1[r] - v0[r];
      const float ctx0 = v0[r] + a01 * dv;
      const float ctx1 = v0[r] + a11 * dv;
      const int col = h * 16 + l15;
      pw[(quad * 4 + r) * 72 + col]      = f2h(ctx0);
      pw[(16 + quad * 4 + r) * 72 + col] = f2h(ctx1);
    }
  }

  // S5: out_proj + residual + LN2 + mean-pool -> pool f16 @0 (ctx dead
  // after ca reads)
  h8 ca[2][2];
#pragma unroll
  for (int mt = 0; mt < 2; ++mt)
#pragma unroll
    for (int ks = 0; ks < 2; ++ks)
      ca[mt][ks] = *(const h8*)(pw + (mt * 16 + l15) * 72 + ks * 32 + quad * 8);
  f4 oacc[2][4];
#pragma unroll
  for (int nt = 0; nt < 4; ++nt) {
    const h8 bf0 = *(const h8*)(wsf + WF_OP + ((0 * 4 + nt) * 64 + lane) * 8);
    const h8 bf1 = *(const h8*)(wsf + WF_OP + ((1 * 4 + nt) * 64 + lane) * 8);
#pragma unroll
    for (int mt = 0; mt < 2; ++mt) {
      f4 acc = {0.f, 0.f, 0.f, 0.f};
      acc = __builtin_amdgcn_mfma_f32_16x16x32_f16(ca[mt][0], bf0, acc, 0, 0, 0);
      acc = __builtin_amdgcn_mfma_f32_16x16x32_f16(ca[mt][1], bf1, acc, 0, 0, 0);
      oacc[mt][nt] = acc;
    }
  }
  float pool[4][4];
#pragma unroll
  for (int mt = 0; mt < 2; ++mt) {
    float val[4][4];
#pragma unroll
    for (int r = 0; r < 4; ++r) {
      if (mt == 0) {
        const int hr = __shfl(hwv, quad * 4 + r);
#pragma unroll
        for (int nt = 0; nt < 4; ++nt)
          val[nt][r] = oacc[0][nt][r] + opbv[nt] + g_hwe[hr * 64 + nt * 16 + l15];
      } else {
#pragma unroll
        for (int nt = 0; nt < 4; ++nt)
          val[nt][r] = oacc[1][nt][r] + opbv[nt] + archres[nt][r];
      }
    }
#pragma unroll
    for (int r = 0; r < 4; ++r) {
      float s = val[0][r] + val[1][r] + val[2][r] + val[3][r];
      float q = val[0][r] * val[0][r] + val[1][r] * val[1][r] +
                val[2][r] * val[2][r] + val[3][r] * val[3][r];
#pragma unroll
      for (int off = 1; off <= 8; off <<= 1) {
        s += __shfl_xor(s, off);
        q += __shfl_xor(q, off);
      }
      const float mean = s * (1.f / 64.f);
      const float var  = q * (1.f / 64.f) - mean * mean;
      const float rstd = rsqrtf(var + 1e-5f);
#pragma unroll
      for (int nt = 0; nt < 4; ++nt) {
        const float xn = (val[nt][r] - mean) * rstd * l2gv[nt] + l2bv[nt];
        if (mt == 0) pool[nt][r] = 0.5f * xn;
        else         pool[nt][r] += 0.5f * xn;
      }
    }
  }
#pragma unroll
  for (int nt = 0; nt < 4; ++nt)
#pragma unroll
    for (int r = 0; r < 4; ++r)
      pw[(quad * 4 + r) * 72 + nt * 16 + l15] = f2h(pool[nt][r]);

  // S6: head
  h8 pa[2];
#pragma unroll
  for (int ks = 0; ks < 2; ++ks)
    pa[ks] = *(const h8*)(pw + l15 * 72 + ks * 32 + quad * 8);
  float part[4] = {0.f, 0.f, 0.f, 0.f};
#pragma unroll
  for (int nt = 0; nt < 2; ++nt) {
    const h8 bf0 = *(const h8*)(wsf + WF_W3 + ((0 * 2 + nt) * 64 + lane) * 8);
    const h8 bf1 = *(const h8*)(wsf + WF_W3 + ((1 * 2 + nt) * 64 + lane) * 8);
    f4 acc = {0.f, 0.f, 0.f, 0.f};
    acc = __builtin_amdgcn_mfma_f32_16x16x32_f16(pa[0], bf0, acc, 0, 0, 0);
    acc = __builtin_amdgcn_mfma_f32_16x16x32_f16(pa[1], bf1, acc, 0, 0, 0);
#pragma unroll
    for (int r = 0; r < 4; ++r) {
      float y = acc[r] + b3v[nt];
      y = y > 0.f ? y : 0.f;
      part[r] += y * w4vv[nt];
    }
  }
#pragma unroll
  for (int off = 1; off <= 8; off <<= 1)
#pragma unroll
    for (int r = 0; r < 4; ++r)
      part[r] += __shfl_xor(part[r], off);
  if (l15 == 0) {
#pragma unroll
    for (int r = 0; r < 4; ++r)
      g_out[m0 + quad * 4 + r] = part[r] + b4v;
  }
}

extern "C" void kernel_launch(void* const* d_in, const int* in_sizes, int n_in,
                              void* d_out, int out_size, void* d_ws, size_t ws_size,
                              hipStream_t stream) {
  (void)in_sizes; (void)n_in; (void)out_size; (void)ws_size;
  unsigned short* ws = (unsigned short*)d_ws;

  k_pre<<<64, 256, 0, stream>>>(
      (const float*)d_in[3], (const float*)d_in[4], (const float*)d_in[5],
      (const float*)d_in[6], (const float*)d_in[10], (const float*)d_in[12],
      (const float*)d_in[16], ws);

  k_fused<<<4096, 256, 0, stream>>>(
      (const int*)d_in[0],
      (const int*)d_in[1], (const int*)d_in[2],
      (const float*)d_in[3],
      (const float*)d_in[7],
      (const float*)d_in[8], (const float*)d_in[9],
      (const float*)d_in[11], (const float*)d_in[13],
      (const float*)d_in[14], (const float*)d_in[15],
      (const float*)d_in[17], (const float*)d_in[18],
      (const float*)d_in[19],
      ws, (float*)d_out);
}

// Round 8
// 172.417 us; speedup vs baseline: 1.5781x; 1.5781x over previous
//
#include <hip/hip_runtime.h>

// ---------------------------------------------------------------------------
// MHLP predictor — fused f16 MFMA; overlay+sigmoid kept, VGPR pin REVERTED.
// (2nd resubmission — R6 and R7 both died on infra: "MI355X container failed
// twice", an acquire-level error. Kernel source unchanged; R5 ran a kernel
// differing by ONE token, R4 ran this launch-bounds config cleanly, so no
// kernel-side mechanism for a container kill. Single-variable discipline ->
// resubmit rather than mutate. If this fails again: rebase on R4-known-good
// and re-apply overlay+sigmoid as separately benched steps.)
// R22 post-mortem (272 us, catastrophic): __launch_bounds__(256,8) forced a
// 64-reg unified VGPR+AGPR budget -> allocator dropped to 32 arch VGPRs and
// SPILLED (WRITE_SIZE 1->414 MB, FETCH 6->245 MB = scratch traffic, 42% HBM).
// Occupancy 87% proved the LDS overlay itself is correct; the pin was the
// only poison. This round: revert to __launch_bounds__(256,4) (budget 128),
// keep overlay (18432 B/block) + sigmoid attention. R4's near-identical body
// chose 64 VGPR under this bound; R5 reduced pressure further, so expect
// <=64 again -> HW can run 8 waves/SIMD unforced (147 KB LDS/CU fits).
// Predict: VGPR ~64, WRITE_SIZE ~1 MB, Occ 50-90%, VALU 75-90%,
// dur ~50-65 us (8 w/SIMD) or ~75-85 (4 w/SIMD); absmax 9.77e-4 unchanged.
// ---------------------------------------------------------------------------

using s8v = __attribute__((ext_vector_type(8))) short;
using h8  = __attribute__((ext_vector_type(8))) _Float16;
using f4  = __attribute__((ext_vector_type(4))) float;

// d_ws u16-unit layout (pre-swizzled f16 weight frags)
#define WF_W1   0        // 12288  (K=75(+bias row 75)->KS=3, NT=8)
#define WF_W2   12288    // 8192   (K=128->KS=4, NT=4)
#define WF_IP   20480    // 12288  (K=64->KS=2, NT=12)
#define WF_OP   32768    // 4096   (K=64->KS=2, NT=4)
#define WF_W3   36864    // 2048   (K=64->KS=2, NT=2)
#define WF_HWE  38912    // 256    (hw_embed f16 [4][64])

// per-wave LDS: single overlaid region
#define PWS     2304     // u16; 4608 B per wave

__device__ __forceinline__ unsigned short f2h(float f) {
  _Float16 h = (_Float16)f;
  return __builtin_bit_cast(unsigned short, h);
}

// swizzle W[N][Kreal] row-major f32 -> B-frag f16 layout; optional bias row
// at k == Kreal (folded-bias trick).
__device__ __forceinline__ void swz(const float* __restrict__ W,
                                    const float* __restrict__ bias,
                                    unsigned short* __restrict__ dst,
                                    int Kreal, int KS, int NT, int t, int stride) {
  const int total = KS * NT * 512;
  for (int i = t; i < total; i += stride) {
    const int j = i & 7, ln = (i >> 3) & 63, fr = i >> 9;
    const int nt = fr % NT, ks = fr / NT;
    const int n = nt * 16 + (ln & 15);
    const int k = ks * 32 + (ln >> 4) * 8 + j;
    float v = 0.f;
    if (k < Kreal) v = W[n * Kreal + k];
    else if (bias && k == Kreal) v = bias[n];
    dst[i] = f2h(v);
  }
}

__global__ void k_pre(const float* __restrict__ hwe,
                      const float* __restrict__ W1, const float* __restrict__ b1,
                      const float* __restrict__ W2,
                      const float* __restrict__ ipw, const float* __restrict__ opw,
                      const float* __restrict__ W3,
                      unsigned short* __restrict__ ws) {
  const int t = blockIdx.x * 256 + threadIdx.x;
  const int stride = gridDim.x * 256;
  swz(W1,  b1,      ws + WF_W1, 75, 3, 8, t, stride);
  swz(W2,  nullptr, ws + WF_W2, 128, 4, 4, t, stride);
  swz(ipw, nullptr, ws + WF_IP, 64, 2, 12, t, stride);
  swz(opw, nullptr, ws + WF_OP, 64, 2, 4, t, stride);
  swz(W3,  nullptr, ws + WF_W3, 64, 2, 2, t, stride);
  for (int i = t; i < 256; i += stride) ws[WF_HWE + i] = f2h(hwe[i]);
}

// ======================= fused: encoder + attention + head =================
__global__ __launch_bounds__(256, 4) void k_fused(
    const int* __restrict__ g_hw,
    const int* __restrict__ g_op, const int* __restrict__ g_wd,
    const float* __restrict__ g_hwe,
    const float* __restrict__ g_b2,
    const float* __restrict__ g_ln1g, const float* __restrict__ g_ln1b,
    const float* __restrict__ g_ipb, const float* __restrict__ g_opb,
    const float* __restrict__ g_ln2g, const float* __restrict__ g_ln2b,
    const float* __restrict__ g_b3,  const float* __restrict__ g_W4,
    const float* __restrict__ g_b4,
    const unsigned short* __restrict__ wsf,   // d_ws base (u16)
    float* __restrict__ g_out) {
  __shared__ __align__(16) unsigned short sm[4 * PWS];
  const int tid = threadIdx.x;
  const int wave = tid >> 6, lane = tid & 63;
  const int quad = lane >> 4, l15 = lane & 15;
  unsigned short* pw = sm + wave * PWS;
  const int m0 = (blockIdx.x * 4 + wave) * 16;   // 4096 blocks x 4 waves

  // ---- index loads (lanes 0..15) + in-wave broadcasts ----
  int hwv = 0, c0 = 0, c1 = 0, c2 = 0, c3 = 0, c4 = 0;
  if (lane < 16) {
    const int smp = m0 + lane;
    hwv = g_hw[smp];
    c0 =      g_op[smp * 5 + 0] * 3 + g_wd[smp * 5 + 0];
    c1 = 15 + g_op[smp * 5 + 1] * 3 + g_wd[smp * 5 + 1];
    c2 = 30 + g_op[smp * 5 + 2] * 3 + g_wd[smp * 5 + 2];
    c3 = 45 + g_op[smp * 5 + 3] * 3 + g_wd[smp * 5 + 3];
    c4 = 60 + g_op[smp * 5 + 4] * 3 + g_wd[smp * 5 + 4];
  }
  const int t0 = __shfl(c0, l15), t1 = __shfl(c1, l15), t2 = __shfl(c2, l15);
  const int t3 = __shfl(c3, l15), t4 = __shfl(c4, l15);
  const int hwrow = __shfl(hwv, l15);

  // ---- hoisted bias/param loads (one burst; L1-resident after 1st block) --
  float b2v[4], l1gv[4], l1bv[4], opbv[4], l2gv[4], l2bv[4];
#pragma unroll
  for (int nt = 0; nt < 4; ++nt) {
    const int col = nt * 16 + l15;
    b2v[nt] = g_b2[col];  l1gv[nt] = g_ln1g[col]; l1bv[nt] = g_ln1b[col];
    opbv[nt] = g_opb[col]; l2gv[nt] = g_ln2g[col]; l2bv[nt] = g_ln2b[col];
  }
  float ipbq[4], ipbvv[4];   // q-bias and v-bias; k-bias cancels in k1-k0
#pragma unroll
  for (int h = 0; h < 4; ++h) {
    ipbq[h]  = g_ipb[h * 16 + l15];
    ipbvv[h] = g_ipb[(h + 8) * 16 + l15];
  }
  float b3v[2], w4vv[2];
#pragma unroll
  for (int nt = 0; nt < 2; ++nt) {
    b3v[nt] = g_b3[nt * 16 + l15];
    w4vv[nt] = g_W4[nt * 16 + l15];
  }
  const float b4v = g_b4[0];

  // ---- one-hot A-frags (k==75 is the folded-bias row, always 1) ----
  h8 aoh[3];
#pragma unroll
  for (int ks = 0; ks < 3; ++ks) {
    s8v a;
#pragma unroll
    for (int j = 0; j < 8; ++j) {
      const int k = ks * 32 + quad * 8 + j;
      const bool hit = (k == 75) || (k == t0) || (k == t1) || (k == t2) ||
                       (k == t3) || (k == t4);
      a[j] = hit ? (short)0x3C00 : (short)0;   // f16 1.0
    }
    aoh[ks] = __builtin_bit_cast(h8, a);
  }

  // S1: h = relu(onehot @ [W1;b1]^T) -> pw[0..2176) stride 136 (f16)
#pragma unroll
  for (int nt = 0; nt < 8; ++nt) {
    f4 acc = {0.f, 0.f, 0.f, 0.f};
#pragma unroll
    for (int ks = 0; ks < 3; ++ks) {
      const h8 bf = *(const h8*)(wsf + WF_W1 + ((ks * 8 + nt) * 64 + lane) * 8);
      acc = __builtin_amdgcn_mfma_f32_16x16x32_f16(aoh[ks], bf, acc, 0, 0, 0);
    }
    const int col = nt * 16 + l15;
#pragma unroll
    for (int r = 0; r < 4; ++r) {
      float v = acc[r];
      v = v > 0.f ? v : 0.f;
      pw[(quad * 4 + r) * 136 + col] = f2h(v);
    }
  }

  // S2: arch = LN1(h @ W2^T + b2); arch f16 -> pw@0 stride 72 (h dead after
  // a2 reads; same-wave DS ops are in-order), residual f32 in regs.
  h8 a2[4];
#pragma unroll
  for (int ks = 0; ks < 4; ++ks)
    a2[ks] = *(const h8*)(pw + l15 * 136 + ks * 32 + quad * 8);
  float archres[4][4];   // LN1 out f32, layout (row=quad*4+r, col=nt*16+l15)
  {
    float val[4][4];
#pragma unroll
    for (int nt = 0; nt < 4; ++nt) {
      f4 acc = {0.f, 0.f, 0.f, 0.f};
#pragma unroll
      for (int ks = 0; ks < 4; ++ks) {
        const h8 bf = *(const h8*)(wsf + WF_W2 + ((ks * 4 + nt) * 64 + lane) * 8);
        acc = __builtin_amdgcn_mfma_f32_16x16x32_f16(a2[ks], bf, acc, 0, 0, 0);
      }
#pragma unroll
      for (int r = 0; r < 4; ++r) val[nt][r] = acc[r] + b2v[nt];
    }
#pragma unroll
    for (int r = 0; r < 4; ++r) {
      float s = val[0][r] + val[1][r] + val[2][r] + val[3][r];
      float q = val[0][r] * val[0][r] + val[1][r] * val[1][r] +
                val[2][r] * val[2][r] + val[3][r] * val[3][r];
#pragma unroll
      for (int off = 1; off <= 8; off <<= 1) {
        s += __shfl_xor(s, off);
        q += __shfl_xor(q, off);
      }
      const float mean = s * (1.f / 64.f);
      const float var  = q * (1.f / 64.f) - mean * mean;
      const float rstd = rsqrtf(var + 1e-5f);
#pragma unroll
      for (int nt = 0; nt < 4; ++nt) {
        const int col = nt * 16 + l15;
        const float xn = (val[nt][r] - mean) * rstd * l1gv[nt] + l1bv[nt];
        archres[nt][r] = xn;
        pw[(quad * 4 + r) * 72 + col] = f2h(xn);
      }
    }
  }

  // S3+S4 fused PER HEAD: qkv MFMAs -> in-register score-diff / sigmoid /
  // ctx. ctx[32][72] f16 -> pw@0 (arch dead after at1 reads).
  h8 at0[2], at1[2];
#pragma unroll
  for (int ks = 0; ks < 2; ++ks) {
    at0[ks] = *(const h8*)(wsf + WF_HWE + hwrow * 64 + ks * 32 + quad * 8);
    at1[ks] = *(const h8*)(pw + l15 * 72 + ks * 32 + quad * 8);
  }
#pragma unroll
  for (int h = 0; h < 4; ++h) {
    f4 aq0 = {0.f,0.f,0.f,0.f}, aq1 = {0.f,0.f,0.f,0.f};
    f4 ak0 = {0.f,0.f,0.f,0.f}, ak1 = {0.f,0.f,0.f,0.f};
    f4 av0 = {0.f,0.f,0.f,0.f}, av1 = {0.f,0.f,0.f,0.f};
#pragma unroll
    for (int ks = 0; ks < 2; ++ks) {
      const h8 bq = *(const h8*)(wsf + WF_IP + ((ks * 12 + h    ) * 64 + lane) * 8);
      const h8 bk = *(const h8*)(wsf + WF_IP + ((ks * 12 + h + 4) * 64 + lane) * 8);
      const h8 bv = *(const h8*)(wsf + WF_IP + ((ks * 12 + h + 8) * 64 + lane) * 8);
      aq0 = __builtin_amdgcn_mfma_f32_16x16x32_f16(at0[ks], bq, aq0, 0, 0, 0);
      aq1 = __builtin_amdgcn_mfma_f32_16x16x32_f16(at1[ks], bq, aq1, 0, 0, 0);
      ak0 = __builtin_amdgcn_mfma_f32_16x16x32_f16(at0[ks], bk, ak0, 0, 0, 0);
      ak1 = __builtin_amdgcn_mfma_f32_16x16x32_f16(at1[ks], bk, ak1, 0, 0, 0);
      av0 = __builtin_amdgcn_mfma_f32_16x16x32_f16(at0[ks], bv, av0, 0, 0, 0);
      av1 = __builtin_amdgcn_mfma_f32_16x16x32_f16(at1[ks], bv, av1, 0, 0, 0);
    }
    // score diffs d[qt] = q[qt]·(k1-k0) (k-bias cancels), reduce over l15
    float d0[4], d1[4], v0[4], v1[4];
#pragma unroll
    for (int r = 0; r < 4; ++r) {
      const float dk = ak1[r] - ak0[r];
      d0[r] = (aq0[r] + ipbq[h]) * dk;
      d1[r] = (aq1[r] + ipbq[h]) * dk;
      v0[r] = av0[r] + ipbvv[h];
      v1[r] = av1[r] + ipbvv[h];
    }
#pragma unroll
    for (int off = 1; off <= 8; off <<= 1)
#pragma unroll
      for (int r = 0; r < 4; ++r) {
        d0[r] += __shfl_xor(d0[r], off);
        d1[r] += __shfl_xor(d1[r], off);
      }
    // softmax over 2 keys == sigmoid(score diff); ctx lane-local
#pragma unroll
    for (int r = 0; r < 4; ++r) {
      const float a01 = 1.f / (1.f + __expf(-d0[r] * 0.25f));
      const float a11 = 1.f / (1.f + __expf(-d1[r] * 0.25f));
      const float dv = v1[r] - v0[r];
      const float ctx0 = v0[r] + a01 * dv;
      const float ctx1 = v0[r] + a11 * dv;
      const int col = h * 16 + l15;
      pw[(quad * 4 + r) * 72 + col]      = f2h(ctx0);
      pw[(16 + quad * 4 + r) * 72 + col] = f2h(ctx1);
    }
  }

  // S5: out_proj + residual + LN2 + mean-pool -> pool f16 @0 (ctx dead
  // after ca reads)
  h8 ca[2][2];
#pragma unroll
  for (int mt = 0; mt < 2; ++mt)
#pragma unroll
    for (int ks = 0; ks < 2; ++ks)
      ca[mt][ks] = *(const h8*)(pw + (mt * 16 + l15) * 72 + ks * 32 + quad * 8);
  f4 oacc[2][4];
#pragma unroll
  for (int nt = 0; nt < 4; ++nt) {
    const h8 bf0 = *(const h8*)(wsf + WF_OP + ((0 * 4 + nt) * 64 + lane) * 8);
    const h8 bf1 = *(const h8*)(wsf + WF_OP + ((1 * 4 + nt) * 64 + lane) * 8);
#pragma unroll
    for (int mt = 0; mt < 2; ++mt) {
      f4 acc = {0.f, 0.f, 0.f, 0.f};
      acc = __builtin_amdgcn_mfma_f32_16x16x32_f16(ca[mt][0], bf0, acc, 0, 0, 0);
      acc = __builtin_amdgcn_mfma_f32_16x16x32_f16(ca[mt][1], bf1, acc, 0, 0, 0);
      oacc[mt][nt] = acc;
    }
  }
  float pool[4][4];
#pragma unroll
  for (int mt = 0; mt < 2; ++mt) {
    float val[4][4];
#pragma unroll
    for (int r = 0; r < 4; ++r) {
      if (mt == 0) {
        const int hr = __shfl(hwv, quad * 4 + r);
#pragma unroll
        for (int nt = 0; nt < 4; ++nt)
          val[nt][r] = oacc[0][nt][r] + opbv[nt] + g_hwe[hr * 64 + nt * 16 + l15];
      } else {
#pragma unroll
        for (int nt = 0; nt < 4; ++nt)
          val[nt][r] = oacc[1][nt][r] + opbv[nt] + archres[nt][r];
      }
    }
#pragma unroll
    for (int r = 0; r < 4; ++r) {
      float s = val[0][r] + val[1][r] + val[2][r] + val[3][r];
      float q = val[0][r] * val[0][r] + val[1][r] * val[1][r] +
                val[2][r] * val[2][r] + val[3][r] * val[3][r];
#pragma unroll
      for (int off = 1; off <= 8; off <<= 1) {
        s += __shfl_xor(s, off);
        q += __shfl_xor(q, off);
      }
      const float mean = s * (1.f / 64.f);
      const float var  = q * (1.f / 64.f) - mean * mean;
      const float rstd = rsqrtf(var + 1e-5f);
#pragma unroll
      for (int nt = 0; nt < 4; ++nt) {
        const float xn = (val[nt][r] - mean) * rstd * l2gv[nt] + l2bv[nt];
        if (mt == 0) pool[nt][r] = 0.5f * xn;
        else         pool[nt][r] += 0.5f * xn;
      }
    }
  }
#pragma unroll
  for (int nt = 0; nt < 4; ++nt)
#pragma unroll
    for (int r = 0; r < 4; ++r)
      pw[(quad * 4 + r) * 72 + nt * 16 + l15] = f2h(pool[nt][r]);

  // S6: head
  h8 pa[2];
#pragma unroll
  for (int ks = 0; ks < 2; ++ks)
    pa[ks] = *(const h8*)(pw + l15 * 72 + ks * 32 + quad * 8);
  float part[4] = {0.f, 0.f, 0.f, 0.f};
#pragma unroll
  for (int nt = 0; nt < 2; ++nt) {
    const h8 bf0 = *(const h8*)(wsf + WF_W3 + ((0 * 2 + nt) * 64 + lane) * 8);
    const h8 bf1 = *(const h8*)(wsf + WF_W3 + ((1 * 2 + nt) * 64 + lane) * 8);
    f4 acc = {0.f, 0.f, 0.f, 0.f};
    acc = __builtin_amdgcn_mfma_f32_16x16x32_f16(pa[0], bf0, acc, 0, 0, 0);
    acc = __builtin_amdgcn_mfma_f32_16x16x32_f16(pa[1], bf1, acc, 0, 0, 0);
#pragma unroll
    for (int r = 0; r < 4; ++r) {
      float y = acc[r] + b3v[nt];
      y = y > 0.f ? y : 0.f;
      part[r] += y * w4vv[nt];
    }
  }
#pragma unroll
  for (int off = 1; off <= 8; off <<= 1)
#pragma unroll
    for (int r = 0; r < 4; ++r)
      part[r] += __shfl_xor(part[r], off);
  if (l15 == 0) {
#pragma unroll
    for (int r = 0; r < 4; ++r)
      g_out[m0 + quad * 4 + r] = part[r] + b4v;
  }
}

extern "C" void kernel_launch(void* const* d_in, const int* in_sizes, int n_in,
                              void* d_out, int out_size, void* d_ws, size_t ws_size,
                              hipStream_t stream) {
  (void)in_sizes; (void)n_in; (void)out_size; (void)ws_size;
  unsigned short* ws = (unsigned short*)d_ws;

  k_pre<<<64, 256, 0, stream>>>(
      (const float*)d_in[3], (const float*)d_in[4], (const float*)d_in[5],
      (const float*)d_in[6], (const float*)d_in[10], (const float*)d_in[12],
      (const float*)d_in[16], ws);

  k_fused<<<4096, 256, 0, stream>>>(
      (const int*)d_in[0],
      (const int*)d_in[1], (const int*)d_in[2],
      (const float*)d_in[3],
      (const float*)d_in[7],
      (const float*)d_in[8], (const float*)d_in[9],
      (const float*)d_in[11], (const float*)d_in[13],
      (const float*)d_in[14], (const float*)d_in[15],
      (const float*)d_in[17], (const float*)d_in[18],
      (const float*)d_in[19],
      ws, (float*)d_out);
}